// Round 6
// baseline (110.755 us; speedup 1.0000x reference)
//
#include <hip/hip_runtime.h>
#include <hip/hip_bf16.h>
#include <math.h>

// Problem constants (match reference)
#define NSAMP 8192
#define BATCH 16
#define CHW   65536
#define EPS_F 1e-12f

// Pair-kernel tiling: 128x128 block tiles over the lower triangle.
// 4 waves per block in a 2x2 arrangement; each wave owns a 64x64 region
// = 4x4 MFMA tiles of 16x16. No LDS in hot loop: fragments + coords in regs.
#define BT    128
#define NBT   (NSAMP / BT)            // 64
#define NINT  (NBT * (NBT - 1) / 2)   // 2016 strictly-interior blocks
#define NBLK  (NINT + NBT)            // 2080 blocks total (64 diagonal)

typedef __attribute__((ext_vector_type(8))) short short8v;  // 8 bf16 = 4 VGPR
typedef __attribute__((ext_vector_type(4))) float f32x4;

// ws layout (bytes):
//   [0, 83200)           : partials double[NBLK*5]
//   [83200, 83204)       : done-counter int (zeroed by prep each call)
//   [86016, 86016+512K)  : XA bf16[8192][32]  row = [hi0..15 | lo0..15]
//   [610304, +64K)       : C2 float[8192][2]  gathered coords
#define OFF_CNT 83200
#define OFF_XA  86016
#define OFF_C2  (OFF_XA + NSAMP * 32 * 2)

// ---------------------------------------------------------------- kernel 1
// One 16-lane group per sample: lane b handles batch b. shfl_xor reductions.
__global__ void __launch_bounds__(256)
prep_kernel(const float* __restrict__ feat, const float* __restrict__ coords,
            const int* __restrict__ sidx,
            __hip_bfloat16* __restrict__ XA, float* __restrict__ C2,
            int* __restrict__ counter) {
    if (blockIdx.x == 0 && threadIdx.x == 0) *counter = 0;  // reset last-block flag
    int t = blockIdx.x * 256 + threadIdx.x;   // 131072 threads total
    int n = t >> 4, b = t & 15;
    int id = sidx[n];
    float v = feat[b * CHW + id];

    float m = v;
    m += __shfl_xor(m, 1, 16); m += __shfl_xor(m, 2, 16);
    m += __shfl_xor(m, 4, 16); m += __shfl_xor(m, 8, 16);
    float c = v - m * (1.0f / 16.0f);
    float q = c * c;
    q += __shfl_xor(q, 1, 16); q += __shfl_xor(q, 2, 16);
    q += __shfl_xor(q, 4, 16); q += __shfl_xor(q, 8, 16);
    float x = c * (1.0f / sqrtf(q));

    // exact split: x = hi + lo + eps, |eps| <= 2^-16 |x|
    __hip_bfloat16 hi = __float2bfloat16(x);
    float hif = __bfloat162float(hi);
    __hip_bfloat16 lo = __float2bfloat16(x - hif);

    XA[n * 32 + b]      = hi;
    XA[n * 32 + 16 + b] = lo;
    if (b == 0) {
        float2 cc = reinterpret_cast<const float2*>(coords)[id];
        reinterpret_cast<float2*>(C2)[n] = cc;
    }
}

// ---------------------------------------------------------------- kernel 2
// a_ij = x_i . x_j via 2 MFMAs (exact fp32 dot, split-bf16), b + moments VALU.
// mfma_f32_16x16x32_bf16: A row = lane&15, k = (lane>>4)*8+e; B col = lane&15,
// same k.  C/D (m89): col = lane&15, row = (lane>>4)*4 + reg.
// [lo|hi] fragment at k-group kg == [hi|lo] row fragment at k-group kg^2.
// Raw v_sqrt_f32/v_rcp_f32 (1-ulp) instead of IEEE sqrtf expansion: result
// feeds 1/(d+1) similarity -> ~1e-7 rel error, negligible vs fp32 reference.
template<bool DIAG>
__device__ __forceinline__ void
compute_tiles(const short* __restrict__ XAs, const float* __restrict__ C2,
              int iW, int jW, int wi, int wj, int col, int kg, int rb,
              float& fSa, float& fSb, float& fSab, float& fSaa, float& fSbb) {
    short8v afr[4];
    float cix[4][4], ciy[4][4];
#pragma unroll
    for (int ti = 0; ti < 4; ++ti) {
        int rowA = iW + ti * 16 + col;
        afr[ti] = *reinterpret_cast<const short8v*>(XAs + rowA * 32 + kg * 8);
        const float4* cp =
            reinterpret_cast<const float4*>(C2 + (iW + ti * 16 + rb) * 2);
        float4 ca = cp[0], cb = cp[1];
        cix[ti][0] = ca.x; ciy[ti][0] = ca.y;
        cix[ti][1] = ca.z; ciy[ti][1] = ca.w;
        cix[ti][2] = cb.x; ciy[ti][2] = cb.y;
        cix[ti][3] = cb.z; ciy[ti][3] = cb.w;
    }
#pragma unroll
    for (int tj = 0; tj < 4; ++tj) {
        int rowB = jW + tj * 16 + col;
        short8v bhl = *reinterpret_cast<const short8v*>(XAs + rowB * 32 + kg * 8);
        short8v blh = *reinterpret_cast<const short8v*>(XAs + rowB * 32 + ((kg ^ 2) * 8));
        int gj = jW + tj * 16 + col;
        float2 cj = reinterpret_cast<const float2*>(C2)[gj];
#pragma unroll
        for (int ti = 0; ti < 4; ++ti) {
            if (DIAG && wi == wj && ti < tj) continue;  // fully-upper tile
            f32x4 acc = {0.f, 0.f, 0.f, 0.f};
            acc = __builtin_amdgcn_mfma_f32_16x16x32_bf16(afr[ti], bhl, acc, 0, 0, 0);
            acc = __builtin_amdgcn_mfma_f32_16x16x32_bf16(afr[ti], blh, acc, 0, 0, 0);
            const int giB = iW + ti * 16 + rb;
#pragma unroll
            for (int r = 0; r < 4; ++r) {
                float a  = acc[r];
                float dx = cix[ti][r] - cj.x, dy = ciy[ti][r] - cj.y;
                float s2 = fmaf(dx, dx, dy * dy);
                s2 = fmaxf(s2, EPS_F);
                float bb = __builtin_amdgcn_rcpf(
                               __builtin_amdgcn_sqrtf(s2) + 1.0f);
                float am = a;
                if (DIAG) {
                    bool mk = (giB + r) > gj;   // strict lower triangle
                    bb = mk ? bb : 0.0f;        // zeroed b kills ab, b, b^2
                    am = mk ? a  : 0.0f;        // zeroed a kills a, a^2
                }
                fSa += am;
                fSb += bb;
                fSab = fmaf(a,  bb, fSab);
                fSaa = fmaf(am, am, fSaa);
                fSbb = fmaf(bb, bb, fSbb);
            }
        }
    }
}

__global__ void __launch_bounds__(256)
pair_kernel(const __hip_bfloat16* __restrict__ XA,
            const float* __restrict__ C2,
            double* __restrict__ partials, int* __restrict__ counter,
            float* __restrict__ out) {
    const bool diag = (blockIdx.x >= NINT);
    int bi, bj;
    if (diag) {
        bi = bj = blockIdx.x - NINT;
    } else {
        int t = blockIdx.x;   // t = bi*(bi-1)/2 + bj, 0 <= bj < bi
        int e = (int)((1.0f + sqrtf(1.0f + 8.0f * (float)t)) * 0.5f);
        while (e * (e - 1) / 2 > t) --e;
        while ((e + 1) * e / 2 <= t) ++e;
        bi = e; bj = t - e * (e - 1) / 2;
    }
    const int slot = blockIdx.x;
    const int tid = threadIdx.x;
    const int wid = tid >> 6, l = tid & 63;
    const int wi = wid >> 1, wj = wid & 1;        // 2x2 wave grid
    const int col = l & 15, kg = l >> 4, rb = kg * 4;

    const int iW = bi * BT + wi * 64;
    const int jW = bj * BT + wj * 64;

    float fSa = 0, fSb = 0, fSab = 0, fSaa = 0, fSbb = 0;
    const short* XAs = reinterpret_cast<const short*>(XA);

    if (diag) {
        if (wj <= wi)   // strictly-upper wave region of diag block: skip
            compute_tiles<true >(XAs, C2, iW, jW, wi, wj, col, kg, rb,
                                 fSa, fSb, fSab, fSaa, fSbb);
    } else {
        compute_tiles<false>(XAs, C2, iW, jW, wi, wj, col, kg, rb,
                             fSa, fSb, fSab, fSaa, fSbb);
    }

    // deterministic block reduction (fp32 partials are bounded, <=256 terms)
    double dSa = fSa, dSb = fSb, dSab = fSab, dSaa = fSaa, dSbb = fSbb;
#pragma unroll
    for (int o = 32; o > 0; o >>= 1) {
        dSa  += __shfl_down(dSa,  o, 64);
        dSb  += __shfl_down(dSb,  o, 64);
        dSab += __shfl_down(dSab, o, 64);
        dSaa += __shfl_down(dSaa, o, 64);
        dSbb += __shfl_down(dSbb, o, 64);
    }
    __shared__ double red[4][5];
    __shared__ int isLast;
    if (l == 0) {
        red[wid][0] = dSa;  red[wid][1] = dSb;  red[wid][2] = dSab;
        red[wid][3] = dSaa; red[wid][4] = dSbb;
    }
    __syncthreads();
    if (tid == 0) {
#pragma unroll
        for (int q = 0; q < 5; ++q)
            partials[slot * 5 + q] =
                red[0][q] + red[1][q] + red[2][q] + red[3][q];
        __threadfence();                      // publish partials (device scope)
        int old = atomicAdd(counter, 1);      // device-scope, cross-XCD safe
        isLast = (old == NBLK - 1);
    }
    __syncthreads();

    // ---- last block folds the finish reduction (saves a 1-block launch) ----
    if (!isLast) return;
    __threadfence();                          // acquire: see all partials
    double s0 = 0, s1 = 0, s2 = 0, s3 = 0, s4 = 0;
    for (int b = tid; b < NBLK; b += 256) {
        s0 += partials[b * 5 + 0]; s1 += partials[b * 5 + 1];
        s2 += partials[b * 5 + 2]; s3 += partials[b * 5 + 3];
        s4 += partials[b * 5 + 4];
    }
#pragma unroll
    for (int o = 32; o > 0; o >>= 1) {
        s0 += __shfl_down(s0, o, 64); s1 += __shfl_down(s1, o, 64);
        s2 += __shfl_down(s2, o, 64); s3 += __shfl_down(s3, o, 64);
        s4 += __shfl_down(s4, o, 64);
    }
    __syncthreads();   // red[] reuse: previous contents consumed above
    if (l == 0) {
        red[wid][0] = s0; red[wid][1] = s1; red[wid][2] = s2;
        red[wid][3] = s3; red[wid][4] = s4;
    }
    __syncthreads();
    if (tid == 0) {
        double Sa  = red[0][0] + red[1][0] + red[2][0] + red[3][0];
        double Sb  = red[0][1] + red[1][1] + red[2][1] + red[3][1];
        double Sab = red[0][2] + red[1][2] + red[2][2] + red[3][2];
        double Saa = red[0][3] + red[1][3] + red[2][3] + red[3][3];
        double Sbb = red[0][4] + red[1][4] + red[2][4] + red[3][4];
        const double cnt = (double)NSAMP * (double)(NSAMP - 1) * 0.5;
        double am = Sa / cnt, bm = Sb / cnt;
        double cov = Sab - cnt * am * bm;
        double va  = Saa - cnt * am * am;
        double vb  = Sbb - cnt * bm * bm;
        double corr = cov / (sqrt(va) * sqrt(vb));
        out[0] = (float)((1.0 - corr) * 0.5);
    }
}

// ---------------------------------------------------------------- launcher
extern "C" void kernel_launch(void* const* d_in, const int* in_sizes, int n_in,
                              void* d_out, int out_size, void* d_ws, size_t ws_size,
                              hipStream_t stream) {
    const float* feat   = (const float*)d_in[0];   // [16,64,32,32] f32
    const float* coords = (const float*)d_in[1];   // [65536,2] f32
    const int*   sidx   = (const int*)d_in[2];     // [8192] int
    float* out = (float*)d_out;

    double* partials = (double*)d_ws;
    int*    counter  = (int*)((char*)d_ws + OFF_CNT);
    __hip_bfloat16* XA = (__hip_bfloat16*)((char*)d_ws + OFF_XA);
    float* C2 = (float*)((char*)d_ws + OFF_C2);

    prep_kernel<<<NSAMP * BATCH / 256, 256, 0, stream>>>(feat, coords, sidx,
                                                         XA, C2, counter);
    pair_kernel<<<NBLK, 256, 0, stream>>>(XA, C2, partials, counter, out);
}

// Round 8
// 89.946 us; speedup vs baseline: 1.2313x; 1.2313x over previous
//
#include <hip/hip_runtime.h>
#include <hip/hip_bf16.h>
#include <math.h>

// Problem constants (match reference)
#define NSAMP 8192
#define BATCH 16
#define CHW   65536
#define EPS_F 1e-12f

// Pair-kernel tiling: 128x128 block tiles over the lower triangle.
// 4 waves per block in a 2x2 arrangement; each wave owns a 64x64 region
// = 4x4 MFMA tiles of 16x16. No LDS in hot loop: fragments + coords in regs.
#define BT    128
#define NBT   (NSAMP / BT)            // 64
#define NINT  (NBT * (NBT - 1) / 2)   // 2016 strictly-interior blocks
#define NBLK  (NINT + NBT)            // 2080 partial slots (+64 diagonal)

typedef __attribute__((ext_vector_type(8))) short short8v;  // 8 bf16 = 4 VGPR
typedef __attribute__((ext_vector_type(4))) float f32x4;

// ws layout (bytes):
//   [0, 83200)           : partials double[NBLK*5]
//   [86016, 86016+512K)  : XA bf16[8192][32]  row = [hi0..15 | lo0..15]
//   [610304, +64K)       : C2 float[8192][2]  gathered coords
#define OFF_XA 86016
#define OFF_C2 (OFF_XA + NSAMP * 32 * 2)

// ---------------------------------------------------------------- kernel 1
// One 16-lane group per sample: lane b handles batch b. shfl_xor reductions.
__global__ void __launch_bounds__(256)
prep_kernel(const float* __restrict__ feat, const float* __restrict__ coords,
            const int* __restrict__ sidx,
            __hip_bfloat16* __restrict__ XA, float* __restrict__ C2) {
    int t = blockIdx.x * 256 + threadIdx.x;   // 131072 threads total
    int n = t >> 4, b = t & 15;
    int id = sidx[n];
    float v = feat[b * CHW + id];

    float m = v;
    m += __shfl_xor(m, 1, 16); m += __shfl_xor(m, 2, 16);
    m += __shfl_xor(m, 4, 16); m += __shfl_xor(m, 8, 16);
    float c = v - m * (1.0f / 16.0f);
    float q = c * c;
    q += __shfl_xor(q, 1, 16); q += __shfl_xor(q, 2, 16);
    q += __shfl_xor(q, 4, 16); q += __shfl_xor(q, 8, 16);
    float x = c * (1.0f / sqrtf(q));

    // exact split: x = hi + lo + eps, |eps| <= 2^-16 |x|
    __hip_bfloat16 hi = __float2bfloat16(x);
    float hif = __bfloat162float(hi);
    __hip_bfloat16 lo = __float2bfloat16(x - hif);

    XA[n * 32 + b]      = hi;
    XA[n * 32 + 16 + b] = lo;
    if (b == 0) {
        float2 cc = reinterpret_cast<const float2*>(coords)[id];
        reinterpret_cast<float2*>(C2)[n] = cc;
    }
}

// ---------------------------------------------------------------- kernel 2
// a_ij = x_i . x_j via 2 MFMAs (exact fp32 dot, split-bf16), b + moments VALU.
// mfma_f32_16x16x32_bf16: A row = lane&15, k = (lane>>4)*8+e; B col = lane&15,
// same k.  C/D (m89): col = lane&15, row = (lane>>4)*4 + reg.
// [lo|hi] fragment at k-group kg == [hi|lo] row fragment at k-group kg^2.
//
// Two-phase body: phase 1 issues ALL global loads into constant-indexed
// register arrays (one vmcnt wait); phase 2 is pure register compute.
// Raw v_sqrt/v_rcp (1-ulp) feed 1/(d+1): ~1e-7 rel err, negligible.
template<bool DIAG>
__device__ __forceinline__ void
compute_tiles(const short* __restrict__ XAs, const float* __restrict__ C2,
              int iW, int jW, int wi, int wj, int col, int kg, int rb,
              float& fSa, float& fSb, float& fSab, float& fSaa, float& fSbb) {
    // ---------------- phase 1: all loads, explicitly hoisted ----------------
    short8v afr[4], bhl[4], blh[4];
    float2 ci[4][4];   // [ti][r] coords of row iW+ti*16+rb+r
    float2 cj[4];      // [tj]    coords of row jW+tj*16+col
#pragma unroll
    for (int ti = 0; ti < 4; ++ti) {
        int rowA = iW + ti * 16 + col;
        afr[ti] = *reinterpret_cast<const short8v*>(XAs + rowA * 32 + kg * 8);
        const float4* cp =
            reinterpret_cast<const float4*>(C2 + (iW + ti * 16 + rb) * 2);
        float4 ca = cp[0], cb = cp[1];
        ci[ti][0] = make_float2(ca.x, ca.y);
        ci[ti][1] = make_float2(ca.z, ca.w);
        ci[ti][2] = make_float2(cb.x, cb.y);
        ci[ti][3] = make_float2(cb.z, cb.w);
    }
#pragma unroll
    for (int tj = 0; tj < 4; ++tj) {
        int rowB = jW + tj * 16 + col;
        bhl[tj] = *reinterpret_cast<const short8v*>(XAs + rowB * 32 + kg * 8);
        blh[tj] = *reinterpret_cast<const short8v*>(XAs + rowB * 32 + ((kg ^ 2) * 8));
        cj[tj]  = reinterpret_cast<const float2*>(C2)[rowB];
    }

    // ---------------- phase 2: pure register compute ----------------
#pragma unroll
    for (int tj = 0; tj < 4; ++tj) {
        const int gj = jW + tj * 16 + col;
        f32x4 acc[4];
#pragma unroll
        for (int ti = 0; ti < 4; ++ti) {
            if (DIAG && wi == wj && ti < tj) continue;   // fully-upper tile
            f32x4 z = {0.f, 0.f, 0.f, 0.f};
            z = __builtin_amdgcn_mfma_f32_16x16x32_bf16(afr[ti], bhl[tj], z, 0, 0, 0);
            z = __builtin_amdgcn_mfma_f32_16x16x32_bf16(afr[ti], blh[tj], z, 0, 0, 0);
            acc[ti] = z;
        }
#pragma unroll
        for (int ti = 0; ti < 4; ++ti) {
            if (DIAG && wi == wj && ti < tj) continue;
            const int giB = iW + ti * 16 + rb;
#pragma unroll
            for (int r = 0; r < 4; ++r) {
                float a  = acc[ti][r];
                float dx = ci[ti][r].x - cj[tj].x;
                float dy = ci[ti][r].y - cj[tj].y;
                float s2 = fmaf(dx, dx, dy * dy);
                s2 = fmaxf(s2, EPS_F);
                float bb = __builtin_amdgcn_rcpf(
                               __builtin_amdgcn_sqrtf(s2) + 1.0f);
                float am = a;
                if (DIAG) {
                    bool mk = (giB + r) > gj;   // strict lower triangle
                    bb = mk ? bb : 0.0f;        // zeroed b kills ab, b, b^2
                    am = mk ? a  : 0.0f;        // zeroed a kills a, a^2
                }
                fSa += am;
                fSb += bb;
                fSab = fmaf(a,  bb, fSab);
                fSaa = fmaf(am, am, fSaa);
                fSbb = fmaf(bb, bb, fSbb);
            }
        }
    }
}

template<bool DIAG>
__global__ void __launch_bounds__(256)
pair_kernel(const __hip_bfloat16* __restrict__ XA,
            const float* __restrict__ C2,
            double* __restrict__ partials) {
    int bi, bj, slot;
    if (DIAG) {
        bi = bj = blockIdx.x; slot = NINT + blockIdx.x;
    } else {
        int t = blockIdx.x;   // t = bi*(bi-1)/2 + bj, 0 <= bj < bi
        int e = (int)((1.0f + sqrtf(1.0f + 8.0f * (float)t)) * 0.5f);
        while (e * (e - 1) / 2 > t) --e;
        while ((e + 1) * e / 2 <= t) ++e;
        bi = e; bj = t - e * (e - 1) / 2; slot = t;
    }
    const int tid = threadIdx.x;
    const int wid = tid >> 6, l = tid & 63;
    const int wi = wid >> 1, wj = wid & 1;        // 2x2 wave grid
    const int col = l & 15, kg = l >> 4, rb = kg * 4;

    const int iW = bi * BT + wi * 64;
    const int jW = bj * BT + wj * 64;

    float fSa = 0, fSb = 0, fSab = 0, fSaa = 0, fSbb = 0;

    if (!(DIAG && wj > wi)) {   // strictly-upper wave region of diag block: skip
        const short* XAs = reinterpret_cast<const short*>(XA);
        compute_tiles<DIAG>(XAs, C2, iW, jW, wi, wj, col, kg, rb,
                            fSa, fSb, fSab, fSaa, fSbb);
    }

    // deterministic block reduction (fp32 partials are bounded, <=256 terms)
    double dSa = fSa, dSb = fSb, dSab = fSab, dSaa = fSaa, dSbb = fSbb;
#pragma unroll
    for (int o = 32; o > 0; o >>= 1) {
        dSa  += __shfl_down(dSa,  o, 64);
        dSb  += __shfl_down(dSb,  o, 64);
        dSab += __shfl_down(dSab, o, 64);
        dSaa += __shfl_down(dSaa, o, 64);
        dSbb += __shfl_down(dSbb, o, 64);
    }
    __shared__ double red[4][5];
    if (l == 0) {
        red[wid][0] = dSa;  red[wid][1] = dSb;  red[wid][2] = dSab;
        red[wid][3] = dSaa; red[wid][4] = dSbb;
    }
    __syncthreads();
    if (tid == 0) {
#pragma unroll
        for (int q = 0; q < 5; ++q)
            partials[slot * 5 + q] =
                red[0][q] + red[1][q] + red[2][q] + red[3][q];
    }
}

// ---------------------------------------------------------------- kernel 3
__global__ void __launch_bounds__(256)
finish_kernel(const double* __restrict__ partials, float* __restrict__ out) {
    double s0 = 0, s1 = 0, s2 = 0, s3 = 0, s4 = 0;
    for (int b = threadIdx.x; b < NBLK; b += 256) {
        s0 += partials[b * 5 + 0]; s1 += partials[b * 5 + 1];
        s2 += partials[b * 5 + 2]; s3 += partials[b * 5 + 3];
        s4 += partials[b * 5 + 4];
    }
    const int lane = threadIdx.x & 63, wid = threadIdx.x >> 6;
#pragma unroll
    for (int o = 32; o > 0; o >>= 1) {
        s0 += __shfl_down(s0, o, 64); s1 += __shfl_down(s1, o, 64);
        s2 += __shfl_down(s2, o, 64); s3 += __shfl_down(s3, o, 64);
        s4 += __shfl_down(s4, o, 64);
    }
    __shared__ double red[4][5];
    if (lane == 0) {
        red[wid][0] = s0; red[wid][1] = s1; red[wid][2] = s2;
        red[wid][3] = s3; red[wid][4] = s4;
    }
    __syncthreads();
    if (threadIdx.x == 0) {
        double Sa  = red[0][0] + red[1][0] + red[2][0] + red[3][0];
        double Sb  = red[0][1] + red[1][1] + red[2][1] + red[3][1];
        double Sab = red[0][2] + red[1][2] + red[2][2] + red[3][2];
        double Saa = red[0][3] + red[1][3] + red[2][3] + red[3][3];
        double Sbb = red[0][4] + red[1][4] + red[2][4] + red[3][4];
        const double cnt = (double)NSAMP * (double)(NSAMP - 1) * 0.5;
        double am = Sa / cnt, bm = Sb / cnt;
        double cov = Sab - cnt * am * bm;
        double va  = Saa - cnt * am * am;
        double vb  = Sbb - cnt * bm * bm;
        double corr = cov / (sqrt(va) * sqrt(vb));
        out[0] = (float)((1.0 - corr) * 0.5);
    }
}

// ---------------------------------------------------------------- launcher
extern "C" void kernel_launch(void* const* d_in, const int* in_sizes, int n_in,
                              void* d_out, int out_size, void* d_ws, size_t ws_size,
                              hipStream_t stream) {
    const float* feat   = (const float*)d_in[0];   // [16,64,32,32] f32
    const float* coords = (const float*)d_in[1];   // [65536,2] f32
    const int*   sidx   = (const int*)d_in[2];     // [8192] int
    float* out = (float*)d_out;

    double* partials = (double*)d_ws;
    __hip_bfloat16* XA = (__hip_bfloat16*)((char*)d_ws + OFF_XA);
    float* C2 = (float*)((char*)d_ws + OFF_C2);

    prep_kernel<<<NSAMP * BATCH / 256, 256, 0, stream>>>(feat, coords, sidx,
                                                         XA, C2);
    pair_kernel<false><<<NINT, 256, 0, stream>>>(XA, C2, partials);
    pair_kernel<true><<<NBT, 256, 0, stream>>>(XA, C2, partials);
    finish_kernel<<<1, 256, 0, stream>>>(partials, out);
}

// Round 9
// 87.480 us; speedup vs baseline: 1.2661x; 1.0282x over previous
//
#include <hip/hip_runtime.h>
#include <hip/hip_bf16.h>
#include <math.h>

// Problem constants (match reference)
#define NSAMP 8192
#define BATCH 16
#define CHW   65536
#define EPS_F 1e-12f

// Pair-kernel tiling: 128x128 block tiles over the lower triangle.
// 4 waves per block in a 2x2 arrangement; each wave owns a 64x64 region
// = 4x4 MFMA tiles of 16x16. No LDS in hot loop: fragments + coords in regs.
#define BT    128
#define NBT   (NSAMP / BT)            // 64
#define NINT  (NBT * (NBT - 1) / 2)   // 2016 strictly-interior blocks
#define NBLK  (NINT + NBT)            // 2080 partial slots (+64 diagonal)

typedef __attribute__((ext_vector_type(8))) short short8v;  // 8 bf16 = 4 VGPR
typedef __attribute__((ext_vector_type(4))) float f32x4;
typedef __attribute__((ext_vector_type(2))) float f32x2;    // -> v_pk_*_f32

// ws layout (bytes):
//   [0, 83200)           : partials double[NBLK*5]
//   [86016, 86016+512K)  : XA bf16[8192][32]  row = [hi0..15 | lo0..15]
//   [610304, +64K)       : C2 float[8192][2]  gathered coords
#define OFF_XA 86016
#define OFF_C2 (OFF_XA + NSAMP * 32 * 2)

// ---------------------------------------------------------------- kernel 1
// One 16-lane group per sample: lane b handles batch b. shfl_xor reductions.
__global__ void __launch_bounds__(256)
prep_kernel(const float* __restrict__ feat, const float* __restrict__ coords,
            const int* __restrict__ sidx,
            __hip_bfloat16* __restrict__ XA, float* __restrict__ C2) {
    int t = blockIdx.x * 256 + threadIdx.x;   // 131072 threads total
    int n = t >> 4, b = t & 15;
    int id = sidx[n];
    float v = feat[b * CHW + id];

    float m = v;
    m += __shfl_xor(m, 1, 16); m += __shfl_xor(m, 2, 16);
    m += __shfl_xor(m, 4, 16); m += __shfl_xor(m, 8, 16);
    float c = v - m * (1.0f / 16.0f);
    float q = c * c;
    q += __shfl_xor(q, 1, 16); q += __shfl_xor(q, 2, 16);
    q += __shfl_xor(q, 4, 16); q += __shfl_xor(q, 8, 16);
    float x = c * (1.0f / sqrtf(q));

    // exact split: x = hi + lo + eps, |eps| <= 2^-16 |x|
    __hip_bfloat16 hi = __float2bfloat16(x);
    float hif = __bfloat162float(hi);
    __hip_bfloat16 lo = __float2bfloat16(x - hif);

    XA[n * 32 + b]      = hi;
    XA[n * 32 + 16 + b] = lo;
    if (b == 0) {
        float2 cc = reinterpret_cast<const float2*>(coords)[id];
        reinterpret_cast<float2*>(C2)[n] = cc;
    }
}

// ---------------------------------------------------------------- kernel 2
// a_ij = x_i . x_j via 2 MFMAs (exact fp32 dot, split-bf16), b + moments VALU.
// mfma_f32_16x16x32_bf16: A row = lane&15, k = (lane>>4)*8+e; B col = lane&15,
// same k.  C/D (m89): col = lane&15, row = (lane>>4)*4 + reg.
// [lo|hi] fragment at k-group kg == [hi|lo] row fragment at k-group kg^2.
//
// Phase 1 hoists ALL global loads into constant-indexed register arrays;
// phase 2 is pure register compute, with the per-pair moment math expressed
// as f32x2 vector arithmetic so the backend can select packed-FP32 VOP3P
// (v_pk_fma_f32 etc., 2 f32 per issue on gfx90a+). Trans ops stay scalar.
// Raw v_sqrt/v_rcp (1-ulp) feed 1/(d+1): ~1e-7 rel err, negligible.
template<bool DIAG>
__device__ __forceinline__ void
compute_tiles(const short* __restrict__ XAs, const float* __restrict__ C2,
              int iW, int jW, int wi, int wj, int col, int kg, int rb,
              f32x2& vSa, f32x2& vSb, f32x2& vSab, f32x2& vSaa, f32x2& vSbb) {
    // ---------------- phase 1: all loads, explicitly hoisted ----------------
    short8v afr[4], bhl[4], blh[4];
    f32x2 cix[4][2], ciy[4][2];  // [ti][p]: x/y of rows (rb+2p, rb+2p+1)
    float2 cj[4];                // [tj] coords of row jW+tj*16+col
#pragma unroll
    for (int ti = 0; ti < 4; ++ti) {
        int rowA = iW + ti * 16 + col;
        afr[ti] = *reinterpret_cast<const short8v*>(XAs + rowA * 32 + kg * 8);
        const float4* cp =
            reinterpret_cast<const float4*>(C2 + (iW + ti * 16 + rb) * 2);
        float4 ca = cp[0], cb = cp[1];   // (x0,y0,x1,y1), (x2,y2,x3,y3)
        cix[ti][0] = (f32x2){ca.x, ca.z};  ciy[ti][0] = (f32x2){ca.y, ca.w};
        cix[ti][1] = (f32x2){cb.x, cb.z};  ciy[ti][1] = (f32x2){cb.y, cb.w};
    }
#pragma unroll
    for (int tj = 0; tj < 4; ++tj) {
        int rowB = jW + tj * 16 + col;
        bhl[tj] = *reinterpret_cast<const short8v*>(XAs + rowB * 32 + kg * 8);
        blh[tj] = *reinterpret_cast<const short8v*>(XAs + rowB * 32 + ((kg ^ 2) * 8));
        cj[tj]  = reinterpret_cast<const float2*>(C2)[rowB];
    }

    // ---------------- phase 2: pure register compute ----------------
#pragma unroll
    for (int tj = 0; tj < 4; ++tj) {
        const int gj = jW + tj * 16 + col;
        const f32x2 cjx = {cj[tj].x, cj[tj].x};
        const f32x2 cjy = {cj[tj].y, cj[tj].y};
        f32x4 acc[4];
#pragma unroll
        for (int ti = 0; ti < 4; ++ti) {
            if (DIAG && wi == wj && ti < tj) continue;   // fully-upper tile
            f32x4 z = {0.f, 0.f, 0.f, 0.f};
            z = __builtin_amdgcn_mfma_f32_16x16x32_bf16(afr[ti], bhl[tj], z, 0, 0, 0);
            z = __builtin_amdgcn_mfma_f32_16x16x32_bf16(afr[ti], blh[tj], z, 0, 0, 0);
            acc[ti] = z;
        }
#pragma unroll
        for (int ti = 0; ti < 4; ++ti) {
            if (DIAG && wi == wj && ti < tj) continue;
            const int giB = iW + ti * 16 + rb;
#pragma unroll
            for (int p = 0; p < 2; ++p) {   // pairs (2p, 2p+1) packed
                f32x2 av = {acc[ti][2 * p], acc[ti][2 * p + 1]};
                f32x2 dx = cix[ti][p] - cjx;
                f32x2 dy = ciy[ti][p] - cjy;
                f32x2 s2 = dx * dx + dy * dy;          // pk_mul + pk_fma
                s2.x = fmaxf(s2.x, EPS_F);
                s2.y = fmaxf(s2.y, EPS_F);
                f32x2 d1;
                d1.x = __builtin_amdgcn_sqrtf(s2.x);
                d1.y = __builtin_amdgcn_sqrtf(s2.y);
                d1 = d1 + (f32x2){1.0f, 1.0f};         // pk_add
                f32x2 bb;
                bb.x = __builtin_amdgcn_rcpf(d1.x);
                bb.y = __builtin_amdgcn_rcpf(d1.y);
                f32x2 am = av;
                if (DIAG) {                 // strict lower triangle mask
                    f32x2 mk = {(giB + 2 * p + 0) > gj ? 1.0f : 0.0f,
                                (giB + 2 * p + 1) > gj ? 1.0f : 0.0f};
                    bb *= mk;               // zeroed b kills ab, b, b^2
                    am *= mk;               // zeroed a kills a, a^2
                }
                vSa += am;
                vSb += bb;
                vSab += av * bb;            // pk_fma (contract)
                vSaa += am * am;
                vSbb += bb * bb;
            }
        }
    }
}

template<bool DIAG>
__global__ void __launch_bounds__(256)
pair_kernel(const __hip_bfloat16* __restrict__ XA,
            const float* __restrict__ C2,
            double* __restrict__ partials) {
    int bi, bj, slot;
    if (DIAG) {
        bi = bj = blockIdx.x; slot = NINT + blockIdx.x;
    } else {
        int t = blockIdx.x;   // t = bi*(bi-1)/2 + bj, 0 <= bj < bi
        int e = (int)((1.0f + sqrtf(1.0f + 8.0f * (float)t)) * 0.5f);
        while (e * (e - 1) / 2 > t) --e;
        while ((e + 1) * e / 2 <= t) ++e;
        bi = e; bj = t - e * (e - 1) / 2; slot = t;
    }
    const int tid = threadIdx.x;
    const int wid = tid >> 6, l = tid & 63;
    const int wi = wid >> 1, wj = wid & 1;        // 2x2 wave grid
    const int col = l & 15, kg = l >> 4, rb = kg * 4;

    const int iW = bi * BT + wi * 64;
    const int jW = bj * BT + wj * 64;

    f32x2 vSa = {0.f, 0.f}, vSb = {0.f, 0.f}, vSab = {0.f, 0.f};
    f32x2 vSaa = {0.f, 0.f}, vSbb = {0.f, 0.f};

    if (!(DIAG && wj > wi)) {   // strictly-upper wave region of diag block: skip
        const short* XAs = reinterpret_cast<const short*>(XA);
        compute_tiles<DIAG>(XAs, C2, iW, jW, wi, wj, col, kg, rb,
                            vSa, vSb, vSab, vSaa, vSbb);
    }

    // deterministic block reduction (fp32 partials are bounded, <=32 terms/half)
    double dSa  = (double)vSa.x  + (double)vSa.y;
    double dSb  = (double)vSb.x  + (double)vSb.y;
    double dSab = (double)vSab.x + (double)vSab.y;
    double dSaa = (double)vSaa.x + (double)vSaa.y;
    double dSbb = (double)vSbb.x + (double)vSbb.y;
#pragma unroll
    for (int o = 32; o > 0; o >>= 1) {
        dSa  += __shfl_down(dSa,  o, 64);
        dSb  += __shfl_down(dSb,  o, 64);
        dSab += __shfl_down(dSab, o, 64);
        dSaa += __shfl_down(dSaa, o, 64);
        dSbb += __shfl_down(dSbb, o, 64);
    }
    __shared__ double red[4][5];
    if (l == 0) {
        red[wid][0] = dSa;  red[wid][1] = dSb;  red[wid][2] = dSab;
        red[wid][3] = dSaa; red[wid][4] = dSbb;
    }
    __syncthreads();
    if (tid == 0) {
#pragma unroll
        for (int q = 0; q < 5; ++q)
            partials[slot * 5 + q] =
                red[0][q] + red[1][q] + red[2][q] + red[3][q];
    }
}

// ---------------------------------------------------------------- kernel 3
__global__ void __launch_bounds__(256)
finish_kernel(const double* __restrict__ partials, float* __restrict__ out) {
    double s0 = 0, s1 = 0, s2 = 0, s3 = 0, s4 = 0;
    for (int b = threadIdx.x; b < NBLK; b += 256) {
        s0 += partials[b * 5 + 0]; s1 += partials[b * 5 + 1];
        s2 += partials[b * 5 + 2]; s3 += partials[b * 5 + 3];
        s4 += partials[b * 5 + 4];
    }
    const int lane = threadIdx.x & 63, wid = threadIdx.x >> 6;
#pragma unroll
    for (int o = 32; o > 0; o >>= 1) {
        s0 += __shfl_down(s0, o, 64); s1 += __shfl_down(s1, o, 64);
        s2 += __shfl_down(s2, o, 64); s3 += __shfl_down(s3, o, 64);
        s4 += __shfl_down(s4, o, 64);
    }
    __shared__ double red[4][5];
    if (lane == 0) {
        red[wid][0] = s0; red[wid][1] = s1; red[wid][2] = s2;
        red[wid][3] = s3; red[wid][4] = s4;
    }
    __syncthreads();
    if (threadIdx.x == 0) {
        double Sa  = red[0][0] + red[1][0] + red[2][0] + red[3][0];
        double Sb  = red[0][1] + red[1][1] + red[2][1] + red[3][1];
        double Sab = red[0][2] + red[1][2] + red[2][2] + red[3][2];
        double Saa = red[0][3] + red[1][3] + red[2][3] + red[3][3];
        double Sbb = red[0][4] + red[1][4] + red[2][4] + red[3][4];
        const double cnt = (double)NSAMP * (double)(NSAMP - 1) * 0.5;
        double am = Sa / cnt, bm = Sb / cnt;
        double cov = Sab - cnt * am * bm;
        double va  = Saa - cnt * am * am;
        double vb  = Sbb - cnt * bm * bm;
        double corr = cov / (sqrt(va) * sqrt(vb));
        out[0] = (float)((1.0 - corr) * 0.5);
    }
}

// ---------------------------------------------------------------- launcher
extern "C" void kernel_launch(void* const* d_in, const int* in_sizes, int n_in,
                              void* d_out, int out_size, void* d_ws, size_t ws_size,
                              hipStream_t stream) {
    const float* feat   = (const float*)d_in[0];   // [16,64,32,32] f32
    const float* coords = (const float*)d_in[1];   // [65536,2] f32
    const int*   sidx   = (const int*)d_in[2];     // [8192] int
    float* out = (float*)d_out;

    double* partials = (double*)d_ws;
    __hip_bfloat16* XA = (__hip_bfloat16*)((char*)d_ws + OFF_XA);
    float* C2 = (float*)((char*)d_ws + OFF_C2);

    prep_kernel<<<NSAMP * BATCH / 256, 256, 0, stream>>>(feat, coords, sidx,
                                                         XA, C2);
    pair_kernel<false><<<NINT, 256, 0, stream>>>(XA, C2, partials);
    pair_kernel<true><<<NBT, 256, 0, stream>>>(XA, C2, partials);
    finish_kernel<<<1, 256, 0, stream>>>(partials, out);
}

// Round 11
// 86.593 us; speedup vs baseline: 1.2790x; 1.0103x over previous
//
#include <hip/hip_runtime.h>
#include <hip/hip_bf16.h>
#include <math.h>

// Problem constants (match reference)
#define NSAMP 8192
#define BATCH 16
#define CHW   65536

// Pair-kernel tiling: 128x128 block tiles over the lower triangle.
// 4 waves per block in a 2x2 arrangement; each wave owns a 64x64 region
// = 4x4 MFMA tiles of 16x16. No LDS in hot loop.
#define BT    128
#define NBT   (NSAMP / BT)            // 64
#define NINT  (NBT * (NBT - 1) / 2)   // 2016 strictly-interior blocks
#define NBLK  (NINT + NBT)            // 2080 partial slots (+64 diagonal)

typedef __attribute__((ext_vector_type(8))) short short8v;  // 8 bf16 = 4 VGPR
typedef __attribute__((ext_vector_type(4))) float f32x4;
typedef __attribute__((ext_vector_type(2))) float f32x2;    // -> v_pk_*_f32

// ws layout (bytes):
//   [0, 83200)           : partials double[NBLK*5]
//   [86016, 86016+512K)  : XA bf16[8192][32]  row = [hi0..15 | lo0..15]
//   [610304, +64K)       : C2 float[8192][2]  gathered coords
#define OFF_XA 86016
#define OFF_C2 (OFF_XA + NSAMP * 32 * 2)

// ---------------------------------------------------------------- kernel 1
// One 16-lane group per sample: lane b handles batch b. shfl_xor reductions.
__global__ void __launch_bounds__(256)
prep_kernel(const float* __restrict__ feat, const float* __restrict__ coords,
            const int* __restrict__ sidx,
            __hip_bfloat16* __restrict__ XA, float* __restrict__ C2) {
    int t = blockIdx.x * 256 + threadIdx.x;   // 131072 threads total
    int n = t >> 4, b = t & 15;
    int id = sidx[n];
    float v = feat[b * CHW + id];

    float m = v;
    m += __shfl_xor(m, 1, 16); m += __shfl_xor(m, 2, 16);
    m += __shfl_xor(m, 4, 16); m += __shfl_xor(m, 8, 16);
    float c = v - m * (1.0f / 16.0f);
    float q = c * c;
    q += __shfl_xor(q, 1, 16); q += __shfl_xor(q, 2, 16);
    q += __shfl_xor(q, 4, 16); q += __shfl_xor(q, 8, 16);
    float x = c * (1.0f / sqrtf(q));

    // exact split: x = hi + lo + eps, |eps| <= 2^-16 |x|
    __hip_bfloat16 hi = __float2bfloat16(x);
    float hif = __bfloat162float(hi);
    __hip_bfloat16 lo = __float2bfloat16(x - hif);

    XA[n * 32 + b]      = hi;
    XA[n * 32 + 16 + b] = lo;
    if (b == 0) {
        float2 cc = reinterpret_cast<const float2*>(coords)[id];
        reinterpret_cast<float2*>(C2)[n] = cc;
    }
}

// ---------------------------------------------------------------- kernel 2
// a_ij = x_i . x_j via 2 MFMAs (exact fp32 dot, split-bf16), b + moments VALU.
// mfma_f32_16x16x32_bf16: A row = lane&15, k = (lane>>4)*8+e; B col = lane&15,
// same k.  C/D (m89): col = lane&15, row = (lane>>4)*4 + reg.
// [lo|hi] fragment at k-group kg == [hi|lo] row fragment at k-group kg^2.
//
// Register-budgeted pipeline (occupancy fix vs R8's full hoist):
//   - hoisted: afr[4] + i-coords (reused across all tj)
//   - tj-rolled: b-fragments + j-coord with explicit DEPTH-1 prefetch
//   - per-ti MFMA consumed immediately (one acc live)
// Target <=128 VGPR -> 4 waves/SIMD (cliff at 128, m69).
// EPS clamp dropped: random-normal coords give s2 >= ~1e-8 >> 1e-12; the
// clamp branch is exact-identical for this data.
template<bool DIAG>
__device__ __forceinline__ void
compute_tiles(const short* __restrict__ XAs, const float* __restrict__ C2,
              int iW, int jW, int wi, int wj, int col, int kg, int rb,
              f32x2& vSa, f32x2& vSb, f32x2& vSab, f32x2& vSaa, f32x2& vSbb) {
    // ---- hoisted i-side state (lives across the whole body) ----
    short8v afr[4];
    f32x2 cix[4][2], ciy[4][2];  // [ti][p]: x/y of rows (rb+2p, rb+2p+1)
#pragma unroll
    for (int ti = 0; ti < 4; ++ti) {
        int rowA = iW + ti * 16 + col;
        afr[ti] = *reinterpret_cast<const short8v*>(XAs + rowA * 32 + kg * 8);
        const float4* cp =
            reinterpret_cast<const float4*>(C2 + (iW + ti * 16 + rb) * 2);
        float4 ca = cp[0], cb = cp[1];   // (x0,y0,x1,y1), (x2,y2,x3,y3)
        cix[ti][0] = (f32x2){ca.x, ca.z};  ciy[ti][0] = (f32x2){ca.y, ca.w};
        cix[ti][1] = (f32x2){cb.x, cb.z};  ciy[ti][1] = (f32x2){cb.y, cb.w};
    }

    // ---- j-side: depth-1 prefetch pipeline over tj ----
    short8v bhl_c = *reinterpret_cast<const short8v*>(
                        XAs + (jW + col) * 32 + kg * 8);
    short8v blh_c = *reinterpret_cast<const short8v*>(
                        XAs + (jW + col) * 32 + ((kg ^ 2) * 8));
    float2  cj_c  = reinterpret_cast<const float2*>(C2)[jW + col];

#pragma unroll
    for (int tj = 0; tj < 4; ++tj) {
        short8v bhl_n, blh_n; float2 cj_n;
        if (tj < 3) {   // issue next-tj loads BEFORE current compute
            int rowB = jW + (tj + 1) * 16 + col;
            bhl_n = *reinterpret_cast<const short8v*>(XAs + rowB * 32 + kg * 8);
            blh_n = *reinterpret_cast<const short8v*>(XAs + rowB * 32 + ((kg ^ 2) * 8));
            cj_n  = reinterpret_cast<const float2*>(C2)[rowB];
        }

        const int gj = jW + tj * 16 + col;
        const f32x2 cjx = {cj_c.x, cj_c.x};
        const f32x2 cjy = {cj_c.y, cj_c.y};
#pragma unroll
        for (int ti = 0; ti < 4; ++ti) {
            if (DIAG && wi == wj && ti < tj) continue;   // fully-upper tile
            f32x4 z = {0.f, 0.f, 0.f, 0.f};
            z = __builtin_amdgcn_mfma_f32_16x16x32_bf16(afr[ti], bhl_c, z, 0, 0, 0);
            z = __builtin_amdgcn_mfma_f32_16x16x32_bf16(afr[ti], blh_c, z, 0, 0, 0);
            const int giB = iW + ti * 16 + rb;
#pragma unroll
            for (int p = 0; p < 2; ++p) {   // pairs (2p, 2p+1) packed
                f32x2 av = {z[2 * p], z[2 * p + 1]};
                f32x2 dx = cix[ti][p] - cjx;
                f32x2 dy = ciy[ti][p] - cjy;
                f32x2 s2 = dx * dx + dy * dy;          // pk_mul + pk_fma
                f32x2 d1;
                d1.x = __builtin_amdgcn_sqrtf(s2.x);
                d1.y = __builtin_amdgcn_sqrtf(s2.y);
                d1 = d1 + (f32x2){1.0f, 1.0f};         // pk_add
                f32x2 bb;
                bb.x = __builtin_amdgcn_rcpf(d1.x);
                bb.y = __builtin_amdgcn_rcpf(d1.y);
                f32x2 am = av;
                if (DIAG) {                 // strict lower triangle mask
                    f32x2 mk = {(giB + 2 * p + 0) > gj ? 1.0f : 0.0f,
                                (giB + 2 * p + 1) > gj ? 1.0f : 0.0f};
                    bb *= mk;               // zeroed b kills ab, b, b^2
                    am *= mk;               // zeroed a kills a, a^2
                }
                vSa += am;
                vSb += bb;
                vSab += av * bb;            // pk_fma
                vSaa += am * am;
                vSbb += bb * bb;
            }
        }
        if (tj < 3) { bhl_c = bhl_n; blh_c = blh_n; cj_c = cj_n; }
    }
}

template<bool DIAG>
__global__ void __launch_bounds__(256, 4)   // cap VGPR<=128 -> 4 waves/SIMD
pair_kernel(const __hip_bfloat16* __restrict__ XA,
            const float* __restrict__ C2,
            double* __restrict__ partials) {
    int bi, bj, slot;
    if (DIAG) {
        bi = bj = blockIdx.x; slot = NINT + blockIdx.x;
    } else {
        int t = blockIdx.x;   // t = bi*(bi-1)/2 + bj, 0 <= bj < bi
        int e = (int)((1.0f + sqrtf(1.0f + 8.0f * (float)t)) * 0.5f);
        while (e * (e - 1) / 2 > t) --e;
        while ((e + 1) * e / 2 <= t) ++e;
        bi = e; bj = t - e * (e - 1) / 2; slot = t;
    }
    const int tid = threadIdx.x;
    const int wid = tid >> 6, l = tid & 63;
    const int wi = wid >> 1, wj = wid & 1;        // 2x2 wave grid
    const int col = l & 15, kg = l >> 4, rb = kg * 4;

    const int iW = bi * BT + wi * 64;
    const int jW = bj * BT + wj * 64;

    f32x2 vSa = {0.f, 0.f}, vSb = {0.f, 0.f}, vSab = {0.f, 0.f};
    f32x2 vSaa = {0.f, 0.f}, vSbb = {0.f, 0.f};

    if (!(DIAG && wj > wi)) {   // strictly-upper wave region of diag block: skip
        const short* XAs = reinterpret_cast<const short*>(XA);
        compute_tiles<DIAG>(XAs, C2, iW, jW, wi, wj, col, kg, rb,
                            vSa, vSb, vSab, vSaa, vSbb);
    }

    // deterministic block reduction (fp32 partials are bounded, <=32 terms/half)
    double dSa  = (double)vSa.x  + (double)vSa.y;
    double dSb  = (double)vSb.x  + (double)vSb.y;
    double dSab = (double)vSab.x + (double)vSab.y;
    double dSaa = (double)vSaa.x + (double)vSaa.y;
    double dSbb = (double)vSbb.x + (double)vSbb.y;
#pragma unroll
    for (int o = 32; o > 0; o >>= 1) {
        dSa  += __shfl_down(dSa,  o, 64);
        dSb  += __shfl_down(dSb,  o, 64);
        dSab += __shfl_down(dSab, o, 64);
        dSaa += __shfl_down(dSaa, o, 64);
        dSbb += __shfl_down(dSbb, o, 64);
    }
    __shared__ double red[4][5];
    if (l == 0) {
        red[wid][0] = dSa;  red[wid][1] = dSb;  red[wid][2] = dSab;
        red[wid][3] = dSaa; red[wid][4] = dSbb;
    }
    __syncthreads();
    if (tid == 0) {
#pragma unroll
        for (int q = 0; q < 5; ++q)
            partials[slot * 5 + q] =
                red[0][q] + red[1][q] + red[2][q] + red[3][q];
    }
}

// ---------------------------------------------------------------- kernel 3
__global__ void __launch_bounds__(256)
finish_kernel(const double* __restrict__ partials, float* __restrict__ out) {
    double s0 = 0, s1 = 0, s2 = 0, s3 = 0, s4 = 0;
    for (int b = threadIdx.x; b < NBLK; b += 256) {
        s0 += partials[b * 5 + 0]; s1 += partials[b * 5 + 1];
        s2 += partials[b * 5 + 2]; s3 += partials[b * 5 + 3];
        s4 += partials[b * 5 + 4];
    }
    const int lane = threadIdx.x & 63, wid = threadIdx.x >> 6;
#pragma unroll
    for (int o = 32; o > 0; o >>= 1) {
        s0 += __shfl_down(s0, o, 64); s1 += __shfl_down(s1, o, 64);
        s2 += __shfl_down(s2, o, 64); s3 += __shfl_down(s3, o, 64);
        s4 += __shfl_down(s4, o, 64);
    }
    __shared__ double red[4][5];
    if (lane == 0) {
        red[wid][0] = s0; red[wid][1] = s1; red[wid][2] = s2;
        red[wid][3] = s3; red[wid][4] = s4;
    }
    __syncthreads();
    if (threadIdx.x == 0) {
        double Sa  = red[0][0] + red[1][0] + red[2][0] + red[3][0];
        double Sb  = red[0][1] + red[1][1] + red[2][1] + red[3][1];
        double Sab = red[0][2] + red[1][2] + red[2][2] + red[3][2];
        double Saa = red[0][3] + red[1][3] + red[2][3] + red[3][3];
        double Sbb = red[0][4] + red[1][4] + red[2][4] + red[3][4];
        const double cnt = (double)NSAMP * (double)(NSAMP - 1) * 0.5;
        double am = Sa / cnt, bm = Sb / cnt;
        double cov = Sab - cnt * am * bm;
        double va  = Saa - cnt * am * am;
        double vb  = Sbb - cnt * bm * bm;
        double corr = cov / (sqrt(va) * sqrt(vb));
        out[0] = (float)((1.0 - corr) * 0.5);
    }
}

// ---------------------------------------------------------------- launcher
extern "C" void kernel_launch(void* const* d_in, const int* in_sizes, int n_in,
                              void* d_out, int out_size, void* d_ws, size_t ws_size,
                              hipStream_t stream) {
    const float* feat   = (const float*)d_in[0];   // [16,64,32,32] f32
    const float* coords = (const float*)d_in[1];   // [65536,2] f32
    const int*   sidx   = (const int*)d_in[2];     // [8192] int
    float* out = (float*)d_out;

    double* partials = (double*)d_ws;
    __hip_bfloat16* XA = (__hip_bfloat16*)((char*)d_ws + OFF_XA);
    float* C2 = (float*)((char*)d_ws + OFF_C2);

    prep_kernel<<<NSAMP * BATCH / 256, 256, 0, stream>>>(feat, coords, sidx,
                                                         XA, C2);
    pair_kernel<false><<<NINT, 256, 0, stream>>>(XA, C2, partials);
    pair_kernel<true><<<NBT, 256, 0, stream>>>(XA, C2, partials);
    finish_kernel<<<1, 256, 0, stream>>>(partials, out);
}

// Round 12
// 86.413 us; speedup vs baseline: 1.2817x; 1.0021x over previous
//
#include <hip/hip_runtime.h>
#include <hip/hip_bf16.h>
#include <math.h>

// Problem constants (match reference)
#define NSAMP 8192
#define BATCH 16
#define CHW   65536

// Pair-kernel tiling: 128x128 block tiles over the lower triangle.
// 4 waves per block in a 2x2 arrangement; each wave owns a 64x64 region
// = 4x4 MFMA tiles of 16x16. Panels staged in LDS (padded stride).
#define BT    128
#define NBT   (NSAMP / BT)            // 64
#define NINT  (NBT * (NBT - 1) / 2)   // 2016 strictly-interior blocks
#define NBLK  (NINT + NBT)            // 2080 partial slots (+64 diagonal)

// LDS row stride for panels: 64 B data + 16 B pad = 80 B = 40 shorts.
// Breaks the 64-B power-of-2 stride so b128 fragment reads are ~2-way max.
#define LROW 40

typedef __attribute__((ext_vector_type(8))) short short8v;  // 8 bf16 = 4 VGPR
typedef __attribute__((ext_vector_type(4))) float f32x4;
typedef __attribute__((ext_vector_type(2))) float f32x2;    // -> v_pk_*_f32

// ws layout (bytes):
//   [0, 83200)           : partials double[NBLK*5]
//   [86016, 86016+512K)  : XA bf16[8192][32]  row = [hi0..15 | lo0..15]
//   [610304, +64K)       : C2 float[8192][2]  gathered coords
#define OFF_XA 86016
#define OFF_C2 (OFF_XA + NSAMP * 32 * 2)

// ---------------------------------------------------------------- kernel 1
// One 16-lane group per sample: lane b handles batch b. shfl_xor reductions.
__global__ void __launch_bounds__(256)
prep_kernel(const float* __restrict__ feat, const float* __restrict__ coords,
            const int* __restrict__ sidx,
            __hip_bfloat16* __restrict__ XA, float* __restrict__ C2) {
    int t = blockIdx.x * 256 + threadIdx.x;   // 131072 threads total
    int n = t >> 4, b = t & 15;
    int id = sidx[n];
    float v = feat[b * CHW + id];

    float m = v;
    m += __shfl_xor(m, 1, 16); m += __shfl_xor(m, 2, 16);
    m += __shfl_xor(m, 4, 16); m += __shfl_xor(m, 8, 16);
    float c = v - m * (1.0f / 16.0f);
    float q = c * c;
    q += __shfl_xor(q, 1, 16); q += __shfl_xor(q, 2, 16);
    q += __shfl_xor(q, 4, 16); q += __shfl_xor(q, 8, 16);
    float x = c * (1.0f / sqrtf(q));

    // exact split: x = hi + lo + eps, |eps| <= 2^-16 |x|
    __hip_bfloat16 hi = __float2bfloat16(x);
    float hif = __bfloat162float(hi);
    __hip_bfloat16 lo = __float2bfloat16(x - hif);

    XA[n * 32 + b]      = hi;
    XA[n * 32 + 16 + b] = lo;
    if (b == 0) {
        float2 cc = reinterpret_cast<const float2*>(coords)[id];
        reinterpret_cast<float2*>(C2)[n] = cc;
    }
}

// ---------------------------------------------------------------- kernel 2
// a_ij = x_i . x_j via 2 MFMAs (exact fp32 dot, split-bf16), b + moments VALU.
// mfma_f32_16x16x32_bf16: A row = lane&15, k = (lane>>4)*8+e; B col = lane&15,
// same k.  C/D (m89): col = lane&15, row = (lane>>4)*4 + reg.
// [lo|hi] fragment at k-group kg == [hi|lo] row fragment at k-group kg^2.
//
// R12: panels staged in LDS once per block (coalesced float4 global loads),
// fragment gathers become fixed-latency ds_read_b128 with no L2 contention.
// Moments in pk-f32 (VOP3P). EPS clamp dropped (exact for gaussian coords).
template<bool DIAG>
__device__ __forceinline__ void
compute_tiles(const short* sA, const short* sB,
              const float2* scA, const float2* scB,
              int iW, int jW, int wi, int wj, int col, int kg, int rb,
              f32x2& vSa, f32x2& vSb, f32x2& vSab, f32x2& vSaa, f32x2& vSbb) {
    // ---- all fragment/coord reads from LDS, fully hoisted ----
    short8v afr[4], bhl[4], blh[4];
    f32x2 cix[4][2], ciy[4][2];  // [ti][p]: x/y of rows (rb+2p, rb+2p+1)
    float2 cj[4];                // [tj] coords of row jW+tj*16+col
#pragma unroll
    for (int ti = 0; ti < 4; ++ti) {
        int rA = wi * 64 + ti * 16;
        afr[ti] = *reinterpret_cast<const short8v*>(sA + (rA + col) * LROW + kg * 8);
        const float4* cp = reinterpret_cast<const float4*>(&scA[rA + rb]);
        float4 ca = cp[0], cb = cp[1];   // (x0,y0,x1,y1), (x2,y2,x3,y3)
        cix[ti][0] = (f32x2){ca.x, ca.z};  ciy[ti][0] = (f32x2){ca.y, ca.w};
        cix[ti][1] = (f32x2){cb.x, cb.z};  ciy[ti][1] = (f32x2){cb.y, cb.w};
    }
#pragma unroll
    for (int tj = 0; tj < 4; ++tj) {
        int rB = wj * 64 + tj * 16 + col;
        bhl[tj] = *reinterpret_cast<const short8v*>(sB + rB * LROW + kg * 8);
        blh[tj] = *reinterpret_cast<const short8v*>(sB + rB * LROW + ((kg ^ 2) * 8));
        cj[tj]  = scB[rB];
    }

    // ---- pure register compute ----
#pragma unroll
    for (int tj = 0; tj < 4; ++tj) {
        const int gj = jW + tj * 16 + col;
        const f32x2 cjx = {cj[tj].x, cj[tj].x};
        const f32x2 cjy = {cj[tj].y, cj[tj].y};
#pragma unroll
        for (int ti = 0; ti < 4; ++ti) {
            if (DIAG && wi == wj && ti < tj) continue;   // fully-upper tile
            f32x4 z = {0.f, 0.f, 0.f, 0.f};
            z = __builtin_amdgcn_mfma_f32_16x16x32_bf16(afr[ti], bhl[tj], z, 0, 0, 0);
            z = __builtin_amdgcn_mfma_f32_16x16x32_bf16(afr[ti], blh[tj], z, 0, 0, 0);
            const int giB = iW + ti * 16 + rb;
#pragma unroll
            for (int p = 0; p < 2; ++p) {   // pairs (2p, 2p+1) packed
                f32x2 av = {z[2 * p], z[2 * p + 1]};
                f32x2 dx = cix[ti][p] - cjx;
                f32x2 dy = ciy[ti][p] - cjy;
                f32x2 s2 = dx * dx + dy * dy;          // pk_mul + pk_fma
                f32x2 d1;
                d1.x = __builtin_amdgcn_sqrtf(s2.x);
                d1.y = __builtin_amdgcn_sqrtf(s2.y);
                d1 = d1 + (f32x2){1.0f, 1.0f};         // pk_add
                f32x2 bb;
                bb.x = __builtin_amdgcn_rcpf(d1.x);
                bb.y = __builtin_amdgcn_rcpf(d1.y);
                f32x2 am = av;
                if (DIAG) {                 // strict lower triangle mask
                    f32x2 mk = {(giB + 2 * p + 0) > gj ? 1.0f : 0.0f,
                                (giB + 2 * p + 1) > gj ? 1.0f : 0.0f};
                    bb *= mk;               // zeroed b kills ab, b, b^2
                    am *= mk;               // zeroed a kills a, a^2
                }
                vSa += am;
                vSb += bb;
                vSab += av * bb;            // pk_fma
                vSaa += am * am;
                vSbb += bb * bb;
            }
        }
    }
}

template<bool DIAG>
__global__ void __launch_bounds__(256, 4)
pair_kernel(const __hip_bfloat16* __restrict__ XA,
            const float* __restrict__ C2,
            double* __restrict__ partials) {
    int bi, bj, slot;
    if (DIAG) {
        bi = bj = blockIdx.x; slot = NINT + blockIdx.x;
    } else {
        int t = blockIdx.x;   // t = bi*(bi-1)/2 + bj, 0 <= bj < bi
        int e = (int)((1.0f + sqrtf(1.0f + 8.0f * (float)t)) * 0.5f);
        while (e * (e - 1) / 2 > t) --e;
        while ((e + 1) * e / 2 <= t) ++e;
        bi = e; bj = t - e * (e - 1) / 2; slot = t;
    }
    const int tid = threadIdx.x;
    const int wid = tid >> 6, l = tid & 63;
    const int wi = wid >> 1, wj = wid & 1;        // 2x2 wave grid
    const int col = l & 15, kg = l >> 4, rb = kg * 4;

    const int iBase = bi * BT, jBase = bj * BT;
    const int iW = iBase + wi * 64;
    const int jW = jBase + wj * 64;

    // ---- LDS panels: 128 rows x 64 B data, 80 B stride (16 B pad) ----
    __shared__ __align__(16) short  sA[BT * LROW];
    __shared__ __align__(16) short  sB[BT * LROW];
    __shared__ __align__(16) float2 scA[BT];
    __shared__ __align__(16) float2 scB[BT];

    const short* XAs = reinterpret_cast<const short*>(XA);
    {   // cooperative stage: thread t -> row t>>1, half (t&1) of 64 B
        const int r = tid >> 1, h = tid & 1;
        const float4* gA =
            reinterpret_cast<const float4*>(XAs + (iBase + r) * 32 + h * 16);
        float4 a0 = gA[0], a1 = gA[1];
        const float4* gB =
            reinterpret_cast<const float4*>(XAs + (jBase + r) * 32 + h * 16);
        float4 b0 = gB[0], b1 = gB[1];
        float4* dA = reinterpret_cast<float4*>(sA + r * LROW + h * 16);
        dA[0] = a0; dA[1] = a1;
        float4* dB = reinterpret_cast<float4*>(sB + r * LROW + h * 16);
        dB[0] = b0; dB[1] = b1;
        if (tid < BT) scA[tid] = reinterpret_cast<const float2*>(C2)[iBase + tid];
        else          scB[tid - BT] =
                          reinterpret_cast<const float2*>(C2)[jBase + (tid - BT)];
    }
    __syncthreads();

    f32x2 vSa = {0.f, 0.f}, vSb = {0.f, 0.f}, vSab = {0.f, 0.f};
    f32x2 vSaa = {0.f, 0.f}, vSbb = {0.f, 0.f};

    if (!(DIAG && wj > wi)) {   // strictly-upper wave region of diag block: skip
        compute_tiles<DIAG>(sA, sB, scA, scB, iW, jW, wi, wj, col, kg, rb,
                            vSa, vSb, vSab, vSaa, vSbb);
    }

    // deterministic block reduction (fp32 partials are bounded, <=32 terms/half)
    double dSa  = (double)vSa.x  + (double)vSa.y;
    double dSb  = (double)vSb.x  + (double)vSb.y;
    double dSab = (double)vSab.x + (double)vSab.y;
    double dSaa = (double)vSaa.x + (double)vSaa.y;
    double dSbb = (double)vSbb.x + (double)vSbb.y;
#pragma unroll
    for (int o = 32; o > 0; o >>= 1) {
        dSa  += __shfl_down(dSa,  o, 64);
        dSb  += __shfl_down(dSb,  o, 64);
        dSab += __shfl_down(dSab, o, 64);
        dSaa += __shfl_down(dSaa, o, 64);
        dSbb += __shfl_down(dSbb, o, 64);
    }
    __shared__ double red[4][5];
    if (l == 0) {
        red[wid][0] = dSa;  red[wid][1] = dSb;  red[wid][2] = dSab;
        red[wid][3] = dSaa; red[wid][4] = dSbb;
    }
    __syncthreads();
    if (tid == 0) {
#pragma unroll
        for (int q = 0; q < 5; ++q)
            partials[slot * 5 + q] =
                red[0][q] + red[1][q] + red[2][q] + red[3][q];
    }
}

// ---------------------------------------------------------------- kernel 3
__global__ void __launch_bounds__(256)
finish_kernel(const double* __restrict__ partials, float* __restrict__ out) {
    double s0 = 0, s1 = 0, s2 = 0, s3 = 0, s4 = 0;
    for (int b = threadIdx.x; b < NBLK; b += 256) {
        s0 += partials[b * 5 + 0]; s1 += partials[b * 5 + 1];
        s2 += partials[b * 5 + 2]; s3 += partials[b * 5 + 3];
        s4 += partials[b * 5 + 4];
    }
    const int lane = threadIdx.x & 63, wid = threadIdx.x >> 6;
#pragma unroll
    for (int o = 32; o > 0; o >>= 1) {
        s0 += __shfl_down(s0, o, 64); s1 += __shfl_down(s1, o, 64);
        s2 += __shfl_down(s2, o, 64); s3 += __shfl_down(s3, o, 64);
        s4 += __shfl_down(s4, o, 64);
    }
    __shared__ double red[4][5];
    if (lane == 0) {
        red[wid][0] = s0; red[wid][1] = s1; red[wid][2] = s2;
        red[wid][3] = s3; red[wid][4] = s4;
    }
    __syncthreads();
    if (threadIdx.x == 0) {
        double Sa  = red[0][0] + red[1][0] + red[2][0] + red[3][0];
        double Sb  = red[0][1] + red[1][1] + red[2][1] + red[3][1];
        double Sab = red[0][2] + red[1][2] + red[2][2] + red[3][2];
        double Saa = red[0][3] + red[1][3] + red[2][3] + red[3][3];
        double Sbb = red[0][4] + red[1][4] + red[2][4] + red[3][4];
        const double cnt = (double)NSAMP * (double)(NSAMP - 1) * 0.5;
        double am = Sa / cnt, bm = Sb / cnt;
        double cov = Sab - cnt * am * bm;
        double va  = Saa - cnt * am * am;
        double vb  = Sbb - cnt * bm * bm;
        double corr = cov / (sqrt(va) * sqrt(vb));
        out[0] = (float)((1.0 - corr) * 0.5);
    }
}

// ---------------------------------------------------------------- launcher
extern "C" void kernel_launch(void* const* d_in, const int* in_sizes, int n_in,
                              void* d_out, int out_size, void* d_ws, size_t ws_size,
                              hipStream_t stream) {
    const float* feat   = (const float*)d_in[0];   // [16,64,32,32] f32
    const float* coords = (const float*)d_in[1];   // [65536,2] f32
    const int*   sidx   = (const int*)d_in[2];     // [8192] int
    float* out = (float*)d_out;

    double* partials = (double*)d_ws;
    __hip_bfloat16* XA = (__hip_bfloat16*)((char*)d_ws + OFF_XA);
    float* C2 = (float*)((char*)d_ws + OFF_C2);

    prep_kernel<<<NSAMP * BATCH / 256, 256, 0, stream>>>(feat, coords, sidx,
                                                         XA, C2);
    pair_kernel<false><<<NINT, 256, 0, stream>>>(XA, C2, partials);
    pair_kernel<true><<<NBT, 256, 0, stream>>>(XA, C2, partials);
    finish_kernel<<<1, 256, 0, stream>>>(partials, out);
}